// Round 8
// baseline (925.385 us; speedup 1.0000x reference)
//
#include <hip/hip_runtime.h>
#include <hip/hip_bf16.h>
#include <cstdint>

// Problem constants
#define BATCH 2048
#define MF    40                 // num fields
#define DDIM  64                 // embedding dim
#define LDIM  128                // hidden size per CIN layer
#define ROWS  (BATCH * DDIM)     // 131072 (b,d) rows

typedef __attribute__((ext_vector_type(4)))  short    short4_t;
typedef __attribute__((ext_vector_type(8)))  short    short8;
typedef __attribute__((ext_vector_type(8)))  __bf16   bf16x8;
typedef __attribute__((ext_vector_type(16))) float    floatx16;
typedef __attribute__((ext_vector_type(4)))  uint32_t uint4_t;

__device__ __forceinline__ unsigned short f32_to_bf16(float f) {
    union { float f; uint32_t u; } v; v.f = f;
    uint32_t u = v.u;
    uint32_t r = (u + 0x7fffu + ((u >> 16) & 1u)) >> 16;   // RNE
    return (unsigned short)r;
}

// scale two packed bf16 (one dword) by fp32 s, round-half-up, repack.
// 7 VALU ops (proven correct rounds 6-7).
__device__ __forceinline__ uint32_t scale2(uint32_t w, float s) {
    float lo = __builtin_bit_cast(float, w << 16);
    float hi = __builtin_bit_cast(float, w & 0xffff0000u);
    uint32_t plo = __builtin_bit_cast(uint32_t, lo * s) + 0x8000u;
    uint32_t phi = __builtin_bit_cast(uint32_t, hi * s) + 0x8000u;
    return __builtin_amdgcn_perm(phi, plo, 0x07060302u);
}

__device__ __forceinline__ bf16x8 scale_frag(bf16x8 a, float s) {
    uint4_t w = __builtin_bit_cast(uint4_t, a);
    uint4_t r;
#pragma unroll
    for (int i = 0; i < 4; ++i) r[i] = scale2(w[i], s);
    return __builtin_bit_cast(bf16x8, r);
}

// ---------------------------------------------------------------------------
// W prep: swizzle W into exact B-fragment order (bf16 RNE, zero-padded h>=H):
//   Wt[m][kk][cb][lane][j] = W[m][ kk*16 + (lane>>5)*8 + j ][ cb*32 + (lane&31) ]
// ---------------------------------------------------------------------------
__global__ void k_wprep(const float* __restrict__ W, unsigned short* __restrict__ Wt,
                        int KK, int H) {
    int bi = blockIdx.x;                 // (m*KK + kk)*4 + cb
    int lane = threadIdx.x;
    int cb = bi & 3;
    int mkk = bi >> 2;
    int kk = mkk % KK, m = mkk / KK;
    int l = cb * 32 + (lane & 31);
    int hbase = kk * 16 + (lane >> 5) * 8;
    unsigned short o[8];
#pragma unroll
    for (int j = 0; j < 8; ++j) {
        int h = hbase + j;
        float v = (h < H) ? W[((size_t)m * H + h) * LDIM + l] : 0.f;
        o[j] = f32_to_bf16(v);
    }
    *(short8*)(Wt + ((size_t)bi * 64 + lane) * 8) = *(const short8*)o;
}

// ---------------------------------------------------------------------------
// Z-GEMM, whole-L waves, NO LDS / NO barriers (free-running waves).
//   out_acc[row,l] = sum_m ( s_m(row) * XK[row,:] ) @ W[m,:,:]   (bf16 MFMA)
// Block = 256 thr = 4 waves; wave w owns batch (blockIdx*4+w): 64 rows x all
// 128 cols. Grid = 512 = exactly 2 blocks/CU.
//   - z = bf16(s_m * xk) built in VALU; one z pair feeds 8 MFMAs directly
//     into acc (no P tile, no epilogue) -> VALU:MFMA ~0.45 per SIMD.
//   - B-frags load STRAIGHT from global (Wt frag-ordered, L1/L2-resident; all
//     waves stream the same sequence) via a 2-slot pair ring, prefetch
//     distance 2 steps (~256 MFMA-cyc) > L1/L2 latency.
//   - no __syncthreads anywhere: rounds 6/7 showed barriers phase-lock the
//     2 waves/SIMD (VALU and MFMA phases collide -> 67% combined util) while
//     free-running waves reach 86% combined. This kernel = R7 ratio in R6
//     barrier-free structure.
// NOTE: (256,2) -> 256 unified regs/wave. (512,4) spilled catastrophically
// in round 3 — do not revisit.
// ---------------------------------------------------------------------------
template <int KK, bool FIRST, int OFF, bool WRITEX>
__global__ __launch_bounds__(256, 2) void k_gemm(
    const float* __restrict__ x,               // fp32 [B][MF][DDIM]
    const unsigned short* __restrict__ Xprev,  // bf16 frag-layout (unused if FIRST)
    const unsigned short* __restrict__ Wt,     // bf16 [MF][KK][4][64][8]
    unsigned short* __restrict__ Xout,         // bf16 frag-layout (unused if !WRITEX)
    float* __restrict__ out)                   // fp32 [B][384]
{
    const int tid  = threadIdx.x;
    const int lane = tid & 63, wave = tid >> 6;
    const int hf   = lane >> 5, r31 = lane & 31;
    const int b = blockIdx.x * 4 + wave;       // this wave's batch

    // ---- A fragments (XK), once: afrag[t][kk], A[row=r31+32t][k=hf*8+j] ----
    bf16x8 afrag[2][KK];
    if constexpr (FIRST) {
#pragma unroll
        for (int t = 0; t < 2; ++t)
#pragma unroll
            for (int kk = 0; kk < KK; ++kk) {
                unsigned short tmp[8];
#pragma unroll
                for (int j = 0; j < 8; ++j) {
                    int h = kk * 16 + hf * 8 + j;
                    float v = (h < MF) ? x[((size_t)b * MF + h) * DDIM + t * 32 + r31] : 0.f;
                    tmp[j] = f32_to_bf16(v);
                }
                afrag[t][kk] = __builtin_bit_cast(bf16x8, *(const short8*)tmp);
            }
    } else {
        const int g = r31 >> 3, hs = (r31 >> 2) & 1, ii = r31 & 3;
#pragma unroll
        for (int t = 0; t < 2; ++t) {
            int tile = b * 2 + t;
#pragma unroll
            for (int kk = 0; kk < KK; ++kk) {
                int k0  = kk * 16 + hf * 8;
                int cbk = k0 >> 5, rr = k0 & 31;
                const unsigned short* p =
                    Xprev + ((size_t)(((tile * 4 + cbk) * 4 + g) * 2 + hs) * 32 + rr) * 4 + ii;
                unsigned short tmp[8];
#pragma unroll
                for (int j = 0; j < 8; ++j) tmp[j] = p[(size_t)j * 4];
                afrag[t][kk] = __builtin_bit_cast(bf16x8, *(const short8*)tmp);
            }
        }
    }

    floatx16 acc[2][4] = {};   // [tile][cb] — direct MFMA accumulators (AGPR)

    auto ldg = [&](int flat_kk, int cb) {      // global B-frag load, frag-ordered
        return __builtin_bit_cast(
            bf16x8, *(const short8*)(Wt + (((size_t)flat_kk * 4 + cb) * 64 + lane) * 8));
    };

    // per-lane scale source: s_m(row=t*32+r31) = x[b][m][t*32+r31]
    const float* sb = x + (size_t)b * MF * DDIM + r31;
    float s0 = sb[0], s1 = sb[32];             // m = 0

    constexpr int NS = 2 * KK;                 // steps per m: (kk, cb-pair)

    // prime the 2-slot pair ring: slot p <- (kk=0, pair p) of m=0
    bf16x8 bbuf[2][2];
#pragma unroll
    for (int p = 0; p < 2; ++p) {
        bbuf[p][0] = ldg(0, p * 2 + 0);
        bbuf[p][1] = ldg(0, p * 2 + 1);
    }

#pragma unroll 1
    for (int m = 0; m < MF; ++m) {
        const int mn = (m + 1 < MF) ? m + 1 : m;           // next m (clamped)
        float snn0 = sb[(size_t)mn * DDIM];                // prefetch next scales
        float snn1 = sb[(size_t)mn * DDIM + 32];

        bf16x8 z0, z1;
#pragma unroll
        for (int s = 0; s < NS; ++s) {
            const int kk = s >> 1, pr = s & 1, slot = s & 1;
            if (pr == 0) {
                z0 = scale_frag(afrag[0][kk], s0);
                z1 = scale_frag(afrag[1][kk], s1);
            }
            acc[0][pr * 2 + 0] = __builtin_amdgcn_mfma_f32_32x32x16_bf16(z0, bbuf[slot][0], acc[0][pr * 2 + 0], 0, 0, 0);
            acc[1][pr * 2 + 0] = __builtin_amdgcn_mfma_f32_32x32x16_bf16(z1, bbuf[slot][0], acc[1][pr * 2 + 0], 0, 0, 0);
            acc[0][pr * 2 + 1] = __builtin_amdgcn_mfma_f32_32x32x16_bf16(z0, bbuf[slot][1], acc[0][pr * 2 + 1], 0, 0, 0);
            acc[1][pr * 2 + 1] = __builtin_amdgcn_mfma_f32_32x32x16_bf16(z1, bbuf[slot][1], acc[1][pr * 2 + 1], 0, 0, 0);
            // prefetch step s+2 (wraps into next m; compile-time branch)
            {
                const int sn = s + 2;
                int kkn, prn, mb;
                if (sn < NS) { kkn = sn >> 1;        prn = sn & 1;        mb = m;  }
                else         { kkn = (sn - NS) >> 1; prn = (sn - NS) & 1; mb = mn; }
                const int flat = mb * KK + kkn;
                bbuf[slot][0] = ldg(flat, prn * 2 + 0);
                bbuf[slot][1] = ldg(flat, prn * 2 + 1);
            }
        }
        s0 = snn0; s1 = snn1;
    }

    // ---- store x_next in C-fragment layout (coalesced b64 stores) ----
    // C/D: col = r31, row = (j&3) + 8*(j>>2) + 4*hf (+32*tile)
    if constexpr (WRITEX) {
#pragma unroll
        for (int t = 0; t < 2; ++t) {
            int tile = b * 2 + t;
#pragma unroll
            for (int cb = 0; cb < 4; ++cb) {
#pragma unroll
                for (int g = 0; g < 4; ++g) {
                    unsigned short o[4];
#pragma unroll
                    for (int i = 0; i < 4; ++i) o[i] = f32_to_bf16(acc[t][cb][g * 4 + i]);
                    *(short4_t*)(Xout +
                        ((size_t)(((tile * 4 + cb) * 4 + g) * 2 + hf) * 32 + r31) * 4) =
                        *(const short4_t*)o;
                }
            }
        }
    }

    // ---- fused ps: out[b][OFF + l] = sum_d acc (fp32, all 64 d in-wave) ----
#pragma unroll
    for (int cb = 0; cb < 4; ++cb) {
        float v = 0.f;
#pragma unroll
        for (int j = 0; j < 16; ++j) v += acc[0][cb][j] + acc[1][cb][j];
        v += __shfl_xor(v, 32);                 // other hf: remaining rows
        if (hf == 0)
            out[(size_t)b * 384 + OFF + cb * 32 + r31] = v;
    }
}

// ---------------------------------------------------------------------------
extern "C" void kernel_launch(void* const* d_in, const int* in_sizes, int n_in,
                              void* d_out, int out_size, void* d_ws, size_t ws_size,
                              hipStream_t stream) {
    const float* x  = (const float*)d_in[0];
    const float* W0 = (const float*)d_in[1];
    const float* W1 = (const float*)d_in[2];
    const float* W2 = (const float*)d_in[3];
    float* out = (float*)d_out;

    char* ws = (char*)d_ws;
    size_t off = 0;
    auto alloc = [&](size_t bytes) -> void* {
        void* p = ws + off;
        off += (bytes + 255) & ~(size_t)255;
        return p;
    };
    unsigned short* W0t = (unsigned short*)alloc((size_t)MF * 3 * 2048 * 2);   // 0.5 MB
    unsigned short* W1t = (unsigned short*)alloc((size_t)MF * 8 * 2048 * 2);   // 1.3 MB
    unsigned short* W2t = (unsigned short*)alloc((size_t)MF * 8 * 2048 * 2);   // 1.3 MB
    unsigned short* X1p = (unsigned short*)alloc((size_t)ROWS * LDIM * 2);     // 33.5 MB
    unsigned short* X2p = (unsigned short*)alloc((size_t)ROWS * LDIM * 2);     // 33.5 MB

    k_wprep<<<MF * 3 * 4, 64, 0, stream>>>(W0, W0t, 3, 40);
    k_wprep<<<MF * 8 * 4, 64, 0, stream>>>(W1, W1t, 8, 128);
    k_wprep<<<MF * 8 * 4, 64, 0, stream>>>(W2, W2t, 8, 128);

    k_gemm<3, true,  0,   true ><<<ROWS / 256, 256, 0, stream>>>(x, nullptr, W0t, X1p, out);
    k_gemm<8, false, 128, true ><<<ROWS / 256, 256, 0, stream>>>(x, X1p,     W1t, X2p, out);
    k_gemm<8, false, 256, false><<<ROWS / 256, 256, 0, stream>>>(x, X2p,     W2t, X2p, out);
}

// Round 9
// 459.996 us; speedup vs baseline: 2.0117x; 2.0117x over previous
//
#include <hip/hip_runtime.h>
#include <hip/hip_bf16.h>
#include <cstdint>

// Problem constants
#define BATCH 2048
#define MF    40                 // num fields
#define DDIM  64                 // embedding dim
#define LDIM  128                // hidden size per CIN layer
#define ROWS  (BATCH * DDIM)     // 131072 (b,d) rows

typedef __attribute__((ext_vector_type(4)))  short    short4_t;
typedef __attribute__((ext_vector_type(8)))  short    short8;
typedef __attribute__((ext_vector_type(8)))  __bf16   bf16x8;
typedef __attribute__((ext_vector_type(4)))  float    floatx4;
typedef __attribute__((ext_vector_type(16))) float    floatx16;

__device__ __forceinline__ unsigned short f32_to_bf16(float f) {
    union { float f; uint32_t u; } v; v.f = f;
    uint32_t u = v.u;
    uint32_t r = (u + 0x7fffu + ((u >> 16) & 1u)) >> 16;   // RNE
    return (unsigned short)r;
}

// raw barrier: execution sync WITHOUT __syncthreads' vmcnt(0)/lgkmcnt(0) drain
__device__ __forceinline__ void barrier_raw() {
    asm volatile("s_barrier" ::: "memory");
}
template <int N> __device__ __forceinline__ void vmwait() {
    if constexpr (N == 0)  asm volatile("s_waitcnt vmcnt(0)"  ::: "memory");
    if constexpr (N == 3)  asm volatile("s_waitcnt vmcnt(3)"  ::: "memory");
    if constexpr (N == 4)  asm volatile("s_waitcnt vmcnt(4)"  ::: "memory");
    if constexpr (N == 11) asm volatile("s_waitcnt vmcnt(11)" ::: "memory");
    if constexpr (N == 12) asm volatile("s_waitcnt vmcnt(12)" ::: "memory");
}

// ---------------------------------------------------------------------------
// W prep: swizzle W into exact B-fragment order (bf16 RNE, zero-padded h>=H):
//   Wt[m][kk][cb][lane][j] = W[m][ kk*16 + (lane>>5)*8 + j ][ cb*32 + (lane&31) ]
// ---------------------------------------------------------------------------
__global__ void k_wprep(const float* __restrict__ W, unsigned short* __restrict__ Wt,
                        int KK, int H) {
    int bi = blockIdx.x;                 // (m*KK + kk)*4 + cb
    int lane = threadIdx.x;
    int cb = bi & 3;
    int mkk = bi >> 2;
    int kk = mkk % KK, m = mkk / KK;
    int l = cb * 32 + (lane & 31);
    int hbase = kk * 16 + (lane >> 5) * 8;
    unsigned short o[8];
#pragma unroll
    for (int j = 0; j < 8; ++j) {
        int h = hbase + j;
        float v = (h < H) ? W[((size_t)m * H + h) * LDIM + l] : 0.f;
        o[j] = f32_to_bf16(v);
    }
    *(short8*)(Wt + ((size_t)bi * 64 + lane) * 8) = *(const short8*)o;
}

// ---------------------------------------------------------------------------
// GEMM + scale + fused column-sum — ring-4 / raw-barrier / counted-vmcnt.
//   out_acc[row,l] = sum_m s_m(row) * (XK[row,:] @ W[m,:,:])[l]
// Block = 256 thr = 4 waves (2x2 over 128 rows x 128 cols); wave: one batch
// (64 rows) x 64 cols. R4's proven math (P tile + fp32 epilogue, low VALU).
// Sync redesign (the 184µs plateau was barrier phase-serialization):
//   - W staged in sub-m units (KU kk's) into a 4-slot LDS ring, issued 3
//     units ahead via global_load_lds x16B.
//   - raw s_barrier per unit (NO vmcnt/lgkm drain) — staging stays in flight
//     across barriers.
//   - correctness via counted s_waitcnt vmcnt(N): per-unit vmem pattern is
//     uniform ([8 sc + KU stage] per m), so "leave newest N" exactly retires
//     stage(u+1) before the barrier that precedes its readers.
//   - register b-frag ring whose prefetch distance reaches across the unit
//     boundary: waves enter each unit with first MFMA operands in regs
//     (no post-barrier ds_read bubble); epilogue overlaps other waves' MFMAs.
// NOTE: (256,2) -> 256 unified regs/wave. (512,4) spilled catastrophically
// in round 3 — do not revisit.
// ---------------------------------------------------------------------------
template <int KK, int KU, bool FIRST, int OFF, bool WRITEX>
__global__ __launch_bounds__(256, 2) void k_gemm(
    const float* __restrict__ x,               // fp32 [B][MF][DDIM]
    const unsigned short* __restrict__ Xprev,  // bf16 frag-layout (unused if FIRST)
    const unsigned short* __restrict__ Wt,     // bf16 [MF][KK][4][64][8]
    unsigned short* __restrict__ Xout,         // bf16 frag-layout (unused if !WRITEX)
    float* __restrict__ out)                   // fp32 [B][384]
{
    constexpr int UPM   = KK / KU;             // units per m (1 or 2)
    constexpr int NU    = MF * UPM;            // total units
    constexpr int DIST  = (KU == 4) ? 2 : 3;   // b-frag reg-ring prefetch dist
    constexpr int SLOTS = (KU == 4) ? 2 : 3;

    __shared__ unsigned short slab[4][KU * 2048];   // 4-slot ring (64/48 KB)

    const int tid  = threadIdx.x;
    const int lane = tid & 63, wave = tid >> 6;
    const int hf   = lane >> 5, r31 = lane & 31;
    const int rowhalf = wave >> 1, colhalf = wave & 1;
    const int b = blockIdx.x * 2 + rowhalf;    // this wave's batch

    // ---- A fragments, once: afrag[t][kk], A[row=r31+32t][k=hf*8+j] ----
    bf16x8 afrag[2][KK];
    if constexpr (FIRST) {
#pragma unroll
        for (int t = 0; t < 2; ++t)
#pragma unroll
            for (int kk = 0; kk < KK; ++kk) {
                unsigned short tmp[8];
#pragma unroll
                for (int j = 0; j < 8; ++j) {
                    int h = kk * 16 + hf * 8 + j;
                    float v = (h < MF) ? x[((size_t)b * MF + h) * DDIM + t * 32 + r31] : 0.f;
                    tmp[j] = f32_to_bf16(v);
                }
                afrag[t][kk] = __builtin_bit_cast(bf16x8, *(const short8*)tmp);
            }
    } else {
        const int g = r31 >> 3, hs = (r31 >> 2) & 1, ii = r31 & 3;
#pragma unroll
        for (int t = 0; t < 2; ++t) {
            int tile = b * 2 + t;
#pragma unroll
            for (int kk = 0; kk < KK; ++kk) {
                int k0  = kk * 16 + hf * 8;
                int cbk = k0 >> 5, rr = k0 & 31;
                const unsigned short* p =
                    Xprev + ((size_t)(((tile * 4 + cbk) * 4 + g) * 2 + hs) * 32 + rr) * 4 + ii;
                unsigned short tmp[8];
#pragma unroll
                for (int j = 0; j < 8; ++j) tmp[j] = p[(size_t)j * 4];
                afrag[t][kk] = __builtin_bit_cast(bf16x8, *(const short8*)tmp);
            }
        }
    }

    floatx16 acc[2][2] = {};   // [tile][cbp]

    auto stage = [&](int uu) {                 // stage unit uu (clamped; KU insts)
        int u = uu < NU ? uu : NU - 1;         // restage of last unit: identical bytes
        const unsigned short* src = Wt + (size_t)u * (KU * 2048);
#pragma unroll
        for (int it = 0; it < KU; ++it) {
            int c = it * 256 + tid;
            __builtin_amdgcn_global_load_lds(
                (const __attribute__((address_space(1))) uint32_t*)(src + (size_t)c * 8),
                (__attribute__((address_space(3))) uint32_t*)(&slab[u & 3][(size_t)c * 8]),
                16, 0, 0);
        }
    };

    const int cbg0 = colhalf * 2, cbg1 = colhalf * 2 + 1;
    auto ldfrag = [&](int u, int frag, int cb) {
        return __builtin_bit_cast(bf16x8,
            *(const short8*)(&slab[u & 3][((size_t)(frag * 4 + cb) * 64 + lane) * 8]));
    };

    // ---- prologue: zero the vm counter baseline, fill 3 ring slots ----
    vmwait<0>();
    stage(0); stage(1); stage(2);
    vmwait<(KU == 4) ? 4 : 3>();               // leave stage(2) -> stage(0,1) retired
    barrier_raw();                             // => ALL waves' stage(0,1) visible

    bf16x8 bbuf[SLOTS][2];                     // register b-frag ring
#pragma unroll
    for (int p = 0; p < SLOTS; ++p) {
        bbuf[p][0] = ldfrag(0, p, cbg0);
        bbuf[p][1] = ldfrag(0, p, cbg1);
    }

    floatx4 sc0[4], sc1[4];

#pragma unroll 1
    for (int m = 0; m < MF; ++m) {
        floatx16 P[2][2] = {};
#pragma unroll
        for (int kk = 0; kk < KK; ++kk) {
            if (kk % KU == 0) {                // unit top (folds in unrolled loop)
                barrier_raw();
                if (kk == 0) {                 // sc: 8 dwordx4, part of the pattern
                    const floatx4* sp4 = (const floatx4*)(x + ((size_t)b * MF + m) * DDIM);
#pragma unroll
                    for (int g = 0; g < 4; ++g) {
                        sc0[g] = sp4[hf + 2 * g];
                        sc1[g] = sp4[8 + hf + 2 * g];
                    }
                }
                stage(m * UPM + kk / KU + 3);  // 3 units ahead in the ring
            }
            const int slot = (KU == 4) ? (kk & 1) : kk;
            P[0][0] = __builtin_amdgcn_mfma_f32_32x32x16_bf16(afrag[0][kk], bbuf[slot][0], P[0][0], 0, 0, 0);
            P[1][0] = __builtin_amdgcn_mfma_f32_32x32x16_bf16(afrag[1][kk], bbuf[slot][0], P[1][0], 0, 0, 0);
            P[0][1] = __builtin_amdgcn_mfma_f32_32x32x16_bf16(afrag[0][kk], bbuf[slot][1], P[0][1], 0, 0, 0);
            P[1][1] = __builtin_amdgcn_mfma_f32_32x32x16_bf16(afrag[1][kk], bbuf[slot][1], P[1][1], 0, 0, 0);
            {   // prefetch DIST kk's ahead (reaches across unit/m boundary)
                const int j  = kk + DIST;               // compile-time
                int mm = m + ((j >= KK) ? 1 : 0);
                if (mm > MF - 1) mm = MF - 1;           // clamp (tail: harmless)
                const int jj = (j >= KK) ? (j - KK) : j;
                const int u  = mm * UPM + jj / KU;
                bbuf[slot][0] = ldfrag(u, jj % KU, cbg0);
                bbuf[slot][1] = ldfrag(u, jj % KU, cbg1);
            }
            if (kk % KU == KU - 1) {           // end-of-unit gate (before next barrier)
                if (KU == 3)      vmwait<11>();    // retire stage(m+2)
                else if (kk == 3) vmwait<12>();    // retire stage(2m+2)
                else              vmwait<4>();     // retire stage(2m+3)
            }
        }
        // fp32 epilogue: acc += s_m(row) * P
        // C/D: col = r31, row = (j&3) + 8*(j>>2) + 4*hf (+32*tile)
#pragma unroll
        for (int cbp = 0; cbp < 2; ++cbp)
#pragma unroll
            for (int g = 0; g < 4; ++g)
#pragma unroll
                for (int i = 0; i < 4; ++i) {
                    acc[0][cbp][g * 4 + i] += sc0[g][i] * P[0][cbp][g * 4 + i];
                    acc[1][cbp][g * 4 + i] += sc1[g][i] * P[1][cbp][g * 4 + i];
                }
    }

    // ---- store x_next in C-fragment layout (coalesced b64 stores) ----
    if constexpr (WRITEX) {
#pragma unroll
        for (int t = 0; t < 2; ++t) {
            int tile = b * 2 + t;
#pragma unroll
            for (int cbp = 0; cbp < 2; ++cbp) {
                int cb = colhalf * 2 + cbp;
#pragma unroll
                for (int g = 0; g < 4; ++g) {
                    unsigned short o[4];
#pragma unroll
                    for (int i = 0; i < 4; ++i) o[i] = f32_to_bf16(acc[t][cbp][g * 4 + i]);
                    *(short4_t*)(Xout +
                        ((size_t)(((tile * 4 + cb) * 4 + g) * 2 + hf) * 32 + r31) * 4) =
                        *(const short4_t*)o;
                }
            }
        }
    }

    // ---- fused ps: out[b][OFF + l] = sum_d acc (fp32, all 64 d in-wave) ----
#pragma unroll
    for (int cbp = 0; cbp < 2; ++cbp) {
        float v = 0.f;
#pragma unroll
        for (int j = 0; j < 16; ++j) v += acc[0][cbp][j] + acc[1][cbp][j];
        v += __shfl_xor(v, 32);                 // other hf: remaining rows
        if (hf == 0)
            out[(size_t)b * 384 + OFF + (colhalf * 2 + cbp) * 32 + r31] = v;
    }
}

// ---------------------------------------------------------------------------
extern "C" void kernel_launch(void* const* d_in, const int* in_sizes, int n_in,
                              void* d_out, int out_size, void* d_ws, size_t ws_size,
                              hipStream_t stream) {
    const float* x  = (const float*)d_in[0];
    const float* W0 = (const float*)d_in[1];
    const float* W1 = (const float*)d_in[2];
    const float* W2 = (const float*)d_in[3];
    float* out = (float*)d_out;

    char* ws = (char*)d_ws;
    size_t off = 0;
    auto alloc = [&](size_t bytes) -> void* {
        void* p = ws + off;
        off += (bytes + 255) & ~(size_t)255;
        return p;
    };
    unsigned short* W0t = (unsigned short*)alloc((size_t)MF * 3 * 2048 * 2);   // 0.5 MB
    unsigned short* W1t = (unsigned short*)alloc((size_t)MF * 8 * 2048 * 2);   // 1.3 MB
    unsigned short* W2t = (unsigned short*)alloc((size_t)MF * 8 * 2048 * 2);   // 1.3 MB
    unsigned short* X1p = (unsigned short*)alloc((size_t)ROWS * LDIM * 2);     // 33.5 MB
    unsigned short* X2p = (unsigned short*)alloc((size_t)ROWS * LDIM * 2);     // 33.5 MB

    k_wprep<<<MF * 3 * 4, 64, 0, stream>>>(W0, W0t, 3, 40);
    k_wprep<<<MF * 8 * 4, 64, 0, stream>>>(W1, W1t, 8, 128);
    k_wprep<<<MF * 8 * 4, 64, 0, stream>>>(W2, W2t, 8, 128);

    k_gemm<3, 3, true,  0,   true ><<<ROWS / 128, 256, 0, stream>>>(x, nullptr, W0t, X1p, out);
    k_gemm<8, 4, false, 128, true ><<<ROWS / 128, 256, 0, stream>>>(x, X1p,     W1t, X2p, out);
    k_gemm<8, 4, false, 256, false><<<ROWS / 128, 256, 0, stream>>>(x, X2p,     W2t, X2p, out);
}